// Round 3
// baseline (148.888 us; speedup 1.0000x reference)
//
#include <hip/hip_runtime.h>

#define BB   256
#define II   1152
#define OO   10
#define DOUT 16

using h2 = __fp16 __attribute__((ext_vector_type(2)));
using h4 = __fp16 __attribute__((ext_vector_type(4)));
using h8 = __fp16 __attribute__((ext_vector_type(8)));
#define H2V(v, a, b) __builtin_shufflevector((v), (v), (a), (b))
#define FD(a, b, c)  __builtin_amdgcn_fdot2((a), (b), (c), false)   // v_dot2_f32_f16

typedef __attribute__((address_space(3))) uint32_t lds_u32_t;
typedef __attribute__((address_space(1))) const uint32_t glb_u32_t;

// width-16 global->LDS DMA: LDS dest = uniform base + lane*16 (linear).
__device__ __forceinline__ void dma16(const __fp16* g, __fp16* l) {
  __builtin_amdgcn_global_load_lds((glb_u32_t*)g, (lds_u32_t*)l, 16, 0, 0);
}

// Cross-lane reduce over the 8 dsub lanes (R1-proven sequence):
// xor1/xor2 on the VALU pipe (DPP quad_perm), xor4 on DS (ds_swizzle).
__device__ __forceinline__ float dpp_add_xor1(float v) {
  int r = __builtin_amdgcn_mov_dpp(__float_as_int(v), 0xB1, 0xF, 0xF, true);
  return v + __int_as_float(r);
}
__device__ __forceinline__ float dpp_add_xor2(float v) {
  int r = __builtin_amdgcn_mov_dpp(__float_as_int(v), 0x4E, 0xF, 0xF, true);
  return v + __int_as_float(r);
}
__device__ __forceinline__ float swz_add_xor4(float v) {
  int r = __builtin_amdgcn_ds_swizzle(__float_as_int(v), 0x101F);
  return v + __int_as_float(r);
}

// squash over the 16 Dout dims held as 8 dsub-lanes x 2 comps; shfl_xor
// reduction (R1 reduce_kernel's proven primitive), same op order as ref.
__device__ __forceinline__ void squash_pair(float v0, float v1,
                                            float& o0, float& o1) {
  float sq = v0 * v0 + v1 * v1;
  sq += __shfl_xor(sq, 1);
  sq += __shfl_xor(sq, 2);
  sq += __shfl_xor(sq, 4);
  const float mag = sqrtf(sq);
  const float t1  = sq / (1.f + sq);
  o0 = t1 * (v0 / (mag + 1e-8f));
  o1 = t1 * (v1 / (mag + 1e-8f));
}

// One-time f32->f16 conversion with layout permute (unchanged from R1).
//   w: [O][I][16][8] f32 -> w16: [I][12(o-pad)][16][8] f16 (3 KB per-i tile)
//   x: [B][I][8] f32     -> x16: [B][I][8] f16 (rtz)
__global__ __launch_bounds__(256) void convert_kernel(
    const float* __restrict__ x, const float* __restrict__ w,
    __fp16* __restrict__ x16, __fp16* __restrict__ w16)
{
  const int bid = blockIdx.x;
  if (bid < 2880) {                       // w part: 11520 rows x 64 float2
    const int t = bid * 256 + threadIdx.x;
    const int e = t & 63;
    const int r = t >> 6;                 // r = o*II + i
    const int o = r / II;
    const int i = r - o * II;
    const float2 v2 = *(const float2*)(w + (size_t)r * 128 + e * 2);
    *(h2*)(w16 + ((size_t)i * 12 + o) * 128 + e * 2) =
        __builtin_amdgcn_cvt_pkrtz(v2.x, v2.y);
  } else {                                // x part: 589824 threads x 4 floats
    const size_t t = (size_t)(bid - 2880) * 256 + threadIdx.x;
    const float4 v4 = *(const float4*)(x + t * 4);
    const h2 a = __builtin_amdgcn_cvt_pkrtz(v4.x, v4.y);
    const h2 c = __builtin_amdgcn_cvt_pkrtz(v4.z, v4.w);
    *(h4*)(x16 + t * 4) = __builtin_shufflevector(a, c, 0, 1, 2, 3);
  }
}

// Pass kernel (R1 skeleton + batched LDS reads + in-prologue V).
// Wave = 8 b x 9 i, block = 4 waves. Grid = 32 icg (fast) x 32 bg = 1024.
// Per-wave triple-buffered 3 KB DMA tiles; 4 VMEM ops per iter -> vmcnt(4).
// K=0: plain sum (c=0.1). K=1: V from plane0. K=2: V from plane0+plane1.
template<int K>
__global__ __launch_bounds__(256, 4) void pass_kernel(
    const __fp16* __restrict__ x16,  // f16 [B][I][8]
    const __fp16* __restrict__ w16,  // f16 [I][12][16][8]
    const float* __restrict__ r0,    // plane0 (K>=1)
    const float* __restrict__ r1,    // plane1 (K==2)
    float* __restrict__ plane)       // f32 [B][O][16] accumulator (pre-zeroed)
{
  const int tid  = threadIdx.x;
  const int lane = tid & 63;
  const int wv   = tid >> 6;
  const int dsub = lane & 7;          // d-pair index (d = 2*dsub + dlo)
  const int bl   = lane >> 3;         // batch-in-wave (8)
  const int icg  = blockIdx.x & 31;   // i-group (4 wave-chunks of 9)
  const int bg   = blockIdx.x >> 5;   // 32 groups of 8 b
  const int b    = bg * 8 + bl;
  const int i0   = (icg * 4 + wv) * 9;

  __shared__ __fp16 wt[4][3 * 1536];  // per-wave 3 bufs x 3 KB = 36.9 KB
  __fp16* const wbuf = wt[wv];

  // V prologue: each lane squashes its own (b, o, d-pair) slice of the
  // previous plane(s). Cross-dispatch coherent (kernel-boundary acquire).
  float Vr[OO][2];
  if (K >= 1) {
#pragma unroll
    for (int o = 0; o < OO; ++o) {
      const float2 a = *(const float2*)(r0 + ((size_t)b * OO + o) * DOUT + dsub * 2);
      float v0, v1;
      squash_pair(a.x, a.y, v0, v1);
      if (K == 2) {
        const float2 c = *(const float2*)(r1 + ((size_t)b * OO + o) * DOUT + dsub * 2);
        float u0, u1;
        squash_pair(c.x, c.y, u0, u1);
        v0 += u0; v1 += u1;            // b-linearity: t(V0+V1) = t(V0)+t(V1)
      }
      Vr[o][0] = v0; Vr[o][1] = v1;
    }
  }

  float s[OO][2];
#pragma unroll
  for (int o = 0; o < OO; ++o) { s[o][0] = 0.f; s[o][1] = 0.f; }

  #define STAGE(i_, ofs_)                                                      \
    {                                                                          \
      const __fp16* gp = w16 + (size_t)(i_) * 1536 + lane * 8;                 \
      dma16(gp,        wbuf + (ofs_));                                         \
      dma16(gp + 512,  wbuf + (ofs_) + 512);                                   \
      dma16(gp + 1024, wbuf + (ofs_) + 1024);                                  \
    }

  const __fp16* xrow = x16 + ((size_t)b * II + i0) * 8;
  STAGE(i0, 0)
  h8 xq = *(const h8*)(xrow);
  asm volatile("" ::: "memory");
  STAGE(i0 + 1, 1536)
  h8 xn = *(const h8*)(xrow + 8);

  int cur = 0;
#pragma unroll 1
  for (int ii = 0; ii < 9; ++ii) {
    // wait: everything except the newest 4 VMEM ops (= next tile's group)
    asm volatile("s_waitcnt vmcnt(4)" ::: "memory");
    __builtin_amdgcn_sched_barrier(0);

    const __fp16* wtb = wbuf + cur * 1536;
    const h2 xq0 = H2V(xq, 0, 1), xq1 = H2V(xq, 2, 3);
    const h2 xq2 = H2V(xq, 4, 5), xq3 = H2V(xq, 6, 7);

    float xh[OO][2];
    float t[OO];
    // Batched-DS pipeline: issue 10 ds_read_b128 (5 o's), fence the
    // scheduler, then compute those 5 o's while the next batch issues.
    // Cuts serial DS-latency chains from 10/iter to ~2/iter.
#pragma unroll
    for (int half = 0; half < 2; ++half) {
      h8 wz[10];
      const __fp16* base = wtb + half * 640 + dsub * 16;   // (o*16+dsub*2)*8
#pragma unroll
      for (int g = 0; g < 5; ++g) {
        wz[2 * g]     = *(const h8*)(base + g * 128);      // d even: 8 c's
        wz[2 * g + 1] = *(const h8*)(base + g * 128 + 8);  // d odd:  8 c's
      }
      __builtin_amdgcn_sched_barrier(0);   // loads stay batched above compute
#pragma unroll
      for (int g = 0; g < 5; ++g) {
        const int o = half * 5 + g;
        xh[o][0] = FD(H2V(wz[2*g], 0, 1), xq0, FD(H2V(wz[2*g], 2, 3), xq1,
                   FD(H2V(wz[2*g], 4, 5), xq2, FD(H2V(wz[2*g], 6, 7), xq3, 0.f))));
        xh[o][1] = FD(H2V(wz[2*g+1], 0, 1), xq0, FD(H2V(wz[2*g+1], 2, 3), xq1,
                   FD(H2V(wz[2*g+1], 4, 5), xq2, FD(H2V(wz[2*g+1], 6, 7), xq3, 0.f))));
        if (K >= 1)
          t[o] = Vr[o][0] * xh[o][0] + Vr[o][1] * xh[o][1];
      }
    }

    if (K == 0) {
#pragma unroll
      for (int o = 0; o < OO; ++o) { s[o][0] += xh[o][0]; s[o][1] += xh[o][1]; }
    } else {
#pragma unroll
      for (int o = 0; o < OO; ++o) {   // reduce over the 8 dsub lanes
        t[o] = dpp_add_xor1(t[o]);
        t[o] = dpp_add_xor2(t[o]);
        t[o] = swz_add_xor4(t[o]);
      }
      float sum = 0.f;
#pragma unroll
      for (int o = 0; o < OO; ++o) { t[o] = __expf(t[o]); sum += t[o]; }
      const float inv = __builtin_amdgcn_rcpf(sum);  // |t|<1 pre-exp; 1-ulp ok
#pragma unroll
      for (int o = 0; o < OO; ++o) {
        const float c = t[o] * inv;
        s[o][0] += c * xh[o][0];
        s[o][1] += c * xh[o][1];
      }
    }

    // issue tile(ii+2): clamped re-stage keeps the VMEM count uniform
    const int inx = (ii < 7) ? (i0 + ii + 2) : (i0 + 8);
    int nbuf = cur - 1; if (nbuf < 0) nbuf += 3;   // (cur+2) % 3
    STAGE(inx, nbuf * 1536)
    xq = xn;
    xn = *(const h8*)(x16 + ((size_t)b * II + inx) * 8);

    cur += 1; if (cur == 3) cur = 0;
  }
  #undef STAGE

  if (K == 0) {
#pragma unroll
    for (int o = 0; o < OO; ++o) { s[o][0] *= 0.1f; s[o][1] *= 0.1f; }
  }

  // drain own DMAs, reuse dead w-buffers for the cross-wave reduce
  asm volatile("s_waitcnt vmcnt(0)" ::: "memory");
  if (wv != 0) {
    float* rr = (float*)&wt[wv][0] + bl * 168;   // padded rows: 2-way banks
#pragma unroll
    for (int o = 0; o < OO; ++o)
      *(float2*)&rr[o * 16 + dsub * 2] = make_float2(s[o][0], s[o][1]);
  }
  __syncthreads();
  if (wv == 0) {
    float* outp = plane + (size_t)b * (OO * DOUT);
#pragma unroll
    for (int o = 0; o < OO; ++o) {
      float a0 = s[o][0], a1 = s[o][1];
#pragma unroll
      for (int r = 1; r < 4; ++r) {
        const float2 v2 = *(const float2*)((const float*)&wt[r][0] +
                                           bl * 168 + o * 16 + dsub * 2);
        a0 += v2.x; a1 += v2.y;
      }
      unsafeAtomicAdd(&outp[o * 16 + dsub * 2],     a0);
      unsafeAtomicAdd(&outp[o * 16 + dsub * 2 + 1], a1);
    }
  }
}

// Final squash of plane2 -> out (R1-proven).
__global__ __launch_bounds__(256) void final_kernel(
    const float* __restrict__ plane,   // [B*O*DOUT]
    float* __restrict__ out)           // fp32 [B*O*DOUT]
{
  const int idx = blockIdx.x * 256 + threadIdx.x;    // over B*O*DOUT = 40960
  const float s = plane[idx];

  float sq = s * s;
  sq += __shfl_xor(sq, 1);
  sq += __shfl_xor(sq, 2);
  sq += __shfl_xor(sq, 4);
  sq += __shfl_xor(sq, 8);
  const float mag = sqrtf(sq);
  out[idx] = sq / (1.f + sq) * (s / (mag + 1e-8f));
}

extern "C" void kernel_launch(void* const* d_in, const int* in_sizes, int n_in,
                              void* d_out, int out_size, void* d_ws, size_t ws_size,
                              hipStream_t stream) {
  const float* x = (const float*)d_in[0];   // fp32 [256,1152,8]
  const float* w = (const float*)d_in[1];   // fp32 [10,1152,16,8]
  float* outp = (float*)d_out;              // fp32 [256,10,16]

  const size_t P = (size_t)BB * OO * DOUT;  // 40960 floats per plane
  float* s0 = (float*)d_ws;                 // 3 accumulator planes
  float* s1 = s0 + P;
  float* s2 = s1 + P;
  __fp16* x16 = (__fp16*)(s2 + P);                 // 4.72 MB
  __fp16* w16 = x16 + (size_t)BB * II * 8;         // 3.54 MB (o-padded tiles)

  hipMemsetAsync(s0, 0, 3 * P * sizeof(float), stream);
  convert_kernel<<<5184, 256, 0, stream>>>(x, w, x16, w16);

  const int pg = 1024;                      // 32 icg (fast) x 32 bg
  const int fg = (int)(P / 256);            // 160 blocks

  pass_kernel<0><<<pg, 256, 0, stream>>>(x16, w16, nullptr, nullptr, s0);
  pass_kernel<1><<<pg, 256, 0, stream>>>(x16, w16, s0, nullptr, s1);
  pass_kernel<2><<<pg, 256, 0, stream>>>(x16, w16, s0, s1, s2);
  final_kernel<<<fg, 256, 0, stream>>>(s2, outp);
}

// Round 4
// 140.702 us; speedup vs baseline: 1.0582x; 1.0582x over previous
//
#include <hip/hip_runtime.h>

#define BB   256
#define II   1152
#define OO   10
#define DOUT 16

using h2 = __fp16 __attribute__((ext_vector_type(2)));
using h4 = __fp16 __attribute__((ext_vector_type(4)));
using h8 = __fp16 __attribute__((ext_vector_type(8)));
#define H2V(v, a, b) __builtin_shufflevector((v), (v), (a), (b))
#define FD(a, b, c)  __builtin_amdgcn_fdot2((a), (b), (c), false)   // v_dot2_f32_f16

typedef __attribute__((address_space(3))) uint32_t lds_u32_t;
typedef __attribute__((address_space(1))) const uint32_t glb_u32_t;

// width-16 global->LDS DMA: LDS dest = uniform base + lane*16 (linear).
__device__ __forceinline__ void dma16(const __fp16* g, __fp16* l) {
  __builtin_amdgcn_global_load_lds((glb_u32_t*)g, (lds_u32_t*)l, 16, 0, 0);
}

// Cross-lane reduce over the 8 dsub lanes (R1/R3-proven sequence):
// xor1/xor2 on the VALU pipe (DPP quad_perm), xor4 on DS (ds_swizzle).
__device__ __forceinline__ float dpp_add_xor1(float v) {
  int r = __builtin_amdgcn_mov_dpp(__float_as_int(v), 0xB1, 0xF, 0xF, true);
  return v + __int_as_float(r);
}
__device__ __forceinline__ float dpp_add_xor2(float v) {
  int r = __builtin_amdgcn_mov_dpp(__float_as_int(v), 0x4E, 0xF, 0xF, true);
  return v + __int_as_float(r);
}
__device__ __forceinline__ float swz_add_xor4(float v) {
  int r = __builtin_amdgcn_ds_swizzle(__float_as_int(v), 0x101F);
  return v + __int_as_float(r);
}

// squash over the 16 Dout dims held as 8 dsub-lanes x 2 comps (R3-proven).
__device__ __forceinline__ void squash_pair(float v0, float v1,
                                            float& o0, float& o1) {
  float sq = v0 * v0 + v1 * v1;
  sq += __shfl_xor(sq, 1);
  sq += __shfl_xor(sq, 2);
  sq += __shfl_xor(sq, 4);
  const float mag = sqrtf(sq);
  const float t1  = sq / (1.f + sq);
  o0 = t1 * (v0 / (mag + 1e-8f));
  o1 = t1 * (v1 / (mag + 1e-8f));
}

// One-time f32->f16 conversion with layout permute (unchanged, proven).
//   w: [O][I][16][8] f32 -> w16: [I][12(o-pad)][16][8] f16 (3 KB per-i tile)
//   x: [B][I][8] f32     -> x16: [B][I][8] f16 (rtz)
__global__ __launch_bounds__(256) void convert_kernel(
    const float* __restrict__ x, const float* __restrict__ w,
    __fp16* __restrict__ x16, __fp16* __restrict__ w16)
{
  const int bid = blockIdx.x;
  if (bid < 2880) {                       // w part: 11520 rows x 64 float2
    const int t = bid * 256 + threadIdx.x;
    const int e = t & 63;
    const int r = t >> 6;                 // r = o*II + i
    const int o = r / II;
    const int i = r - o * II;
    const float2 v2 = *(const float2*)(w + (size_t)r * 128 + e * 2);
    *(h2*)(w16 + ((size_t)i * 12 + o) * 128 + e * 2) =
        __builtin_amdgcn_cvt_pkrtz(v2.x, v2.y);
  } else {                                // x part: 589824 threads x 4 floats
    const size_t t = (size_t)(bid - 2880) * 256 + threadIdx.x;
    const float4 v4 = *(const float4*)(x + t * 4);
    const h2 a = __builtin_amdgcn_cvt_pkrtz(v4.x, v4.y);
    const h2 c = __builtin_amdgcn_cvt_pkrtz(v4.z, v4.w);
    *(h4*)(x16 + t * 4) = __builtin_shufflevector(a, c, 0, 1, 2, 3);
  }
}

// Kernel A: the einsum, computed ONCE. R3 K=0 skeleton (proven) + f16 xh
// store. xh layout [I][O][B][16] f16: per-(i,o) wave store is lane-linear
// 256 B (fully coalesced dword). plane0 accumulates 0.1 * sum_i xh (f32).
__global__ __launch_bounds__(256, 4) void einsum_kernel(
    const __fp16* __restrict__ x16,  // f16 [B][I][8]
    const __fp16* __restrict__ w16,  // f16 [I][12][16][8]
    __fp16* __restrict__ xh16,       // f16 [I][O][B][16] out
    float* __restrict__ plane)       // f32 [B][O][16] accumulator (pre-zeroed)
{
  const int tid  = threadIdx.x;
  const int lane = tid & 63;
  const int wv   = tid >> 6;
  const int dsub = lane & 7;          // d-pair index (d = 2*dsub + dlo)
  const int bl   = lane >> 3;         // batch-in-wave (8)
  const int icg  = blockIdx.x & 31;   // i-group (4 wave-chunks of 9)
  const int bg   = blockIdx.x >> 5;   // 32 groups of 8 b
  const int b    = bg * 8 + bl;
  const int i0   = (icg * 4 + wv) * 9;
  const int lb   = b * 16 + dsub * 2; // lane's element offset within an (i,o) row

  __shared__ __fp16 wt[4][3 * 1536];  // per-wave 3 bufs x 3 KB = 36.9 KB
  __fp16* const wbuf = wt[wv];

  float s[OO][2];
#pragma unroll
  for (int o = 0; o < OO; ++o) { s[o][0] = 0.f; s[o][1] = 0.f; }

  #define STAGE(i_, ofs_)                                                      \
    {                                                                          \
      const __fp16* gp = w16 + (size_t)(i_) * 1536 + lane * 8;                 \
      dma16(gp,        wbuf + (ofs_));                                         \
      dma16(gp + 512,  wbuf + (ofs_) + 512);                                   \
      dma16(gp + 1024, wbuf + (ofs_) + 1024);                                  \
    }

  const __fp16* xrow = x16 + ((size_t)b * II + i0) * 8;
  STAGE(i0, 0)
  h8 xq = *(const h8*)(xrow);
  asm volatile("" ::: "memory");
  STAGE(i0 + 1, 1536)
  h8 xn = *(const h8*)(xrow + 8);

  int cur = 0;
#pragma unroll 1
  for (int ii = 0; ii < 9; ++ii) {
    // wait: everything except the newest 4 VMEM ops (= next tile's DMA group).
    // Stores issued last iter are OLDER than those 4 -> also drained (fine).
    asm volatile("s_waitcnt vmcnt(4)" ::: "memory");
    __builtin_amdgcn_sched_barrier(0);

    const int i = i0 + ii;
    const __fp16* wtb = wbuf + cur * 1536;
    const h2 xq0 = H2V(xq, 0, 1), xq1 = H2V(xq, 2, 3);
    const h2 xq2 = H2V(xq, 4, 5), xq3 = H2V(xq, 6, 7);

    float xh[OO][2];
#pragma unroll
    for (int half = 0; half < 2; ++half) {
      h8 wz[10];
      const __fp16* base = wtb + half * 640 + dsub * 16;   // (o*16+dsub*2)*8
#pragma unroll
      for (int g = 0; g < 5; ++g) {
        wz[2 * g]     = *(const h8*)(base + g * 128);      // d even: 8 c's
        wz[2 * g + 1] = *(const h8*)(base + g * 128 + 8);  // d odd:  8 c's
      }
      __builtin_amdgcn_sched_barrier(0);   // loads stay batched above compute
#pragma unroll
      for (int g = 0; g < 5; ++g) {
        const int o = half * 5 + g;
        xh[o][0] = FD(H2V(wz[2*g], 0, 1), xq0, FD(H2V(wz[2*g], 2, 3), xq1,
                   FD(H2V(wz[2*g], 4, 5), xq2, FD(H2V(wz[2*g], 6, 7), xq3, 0.f))));
        xh[o][1] = FD(H2V(wz[2*g+1], 0, 1), xq0, FD(H2V(wz[2*g+1], 2, 3), xq1,
                   FD(H2V(wz[2*g+1], 4, 5), xq2, FD(H2V(wz[2*g+1], 6, 7), xq3, 0.f))));
      }
    }

    // accumulate plane0 partial (f32, same as R3-verified K=0 path)
#pragma unroll
    for (int o = 0; o < OO; ++o) { s[o][0] += xh[o][0]; s[o][1] += xh[o][1]; }

    // store xh to global (f16): 10 coalesced dword stores, before STAGE so
    // the vmcnt(4) tile logic stays valid.
    {
      __fp16* op = xh16 + (size_t)i * (OO * 4096) + lb;
#pragma unroll
      for (int o = 0; o < OO; ++o)
        *(h2*)(op + o * 4096) = __builtin_amdgcn_cvt_pkrtz(xh[o][0], xh[o][1]);
    }

    // issue tile(ii+2): clamped re-stage keeps the VMEM count uniform
    const int inx = (ii < 7) ? (i0 + ii + 2) : (i0 + 8);
    int nbuf = cur - 1; if (nbuf < 0) nbuf += 3;   // (cur+2) % 3
    STAGE(inx, nbuf * 1536)
    xq = xn;
    xn = *(const h8*)(x16 + ((size_t)b * II + inx) * 8);

    cur += 1; if (cur == 3) cur = 0;
  }
  #undef STAGE

#pragma unroll
  for (int o = 0; o < OO; ++o) { s[o][0] *= 0.1f; s[o][1] *= 0.1f; }

  // drain own DMAs/stores, reuse dead w-buffers for the cross-wave reduce
  asm volatile("s_waitcnt vmcnt(0)" ::: "memory");
  if (wv != 0) {
    float* rr = (float*)&wt[wv][0] + bl * 168;   // padded rows: 2-way banks
#pragma unroll
    for (int o = 0; o < OO; ++o)
      *(float2*)&rr[o * 16 + dsub * 2] = make_float2(s[o][0], s[o][1]);
  }
  __syncthreads();
  if (wv == 0) {
    float* outp = plane + (size_t)b * (OO * DOUT);
#pragma unroll
    for (int o = 0; o < OO; ++o) {
      float a0 = s[o][0], a1 = s[o][1];
#pragma unroll
      for (int r = 1; r < 4; ++r) {
        const float2 v2 = *(const float2*)((const float*)&wt[r][0] +
                                           bl * 168 + o * 16 + dsub * 2);
        a0 += v2.x; a1 += v2.y;
      }
      unsafeAtomicAdd(&outp[o * 16 + dsub * 2],     a0);
      unsafeAtomicAdd(&outp[o * 16 + dsub * 2 + 1], a1);
    }
  }
}

// Kernels B/C: routing passes as pure xh streamers (memory-bound).
// K=1: V from plane0. K=2: V from plane0+plane1.
template<int K>
__global__ __launch_bounds__(256, 4) void route_kernel(
    const __fp16* __restrict__ xh16, // f16 [I][O][B][16]
    const float* __restrict__ r0,    // plane0
    const float* __restrict__ r1,    // plane1 (K==2)
    float* __restrict__ plane)       // output plane accumulator (pre-zeroed)
{
  const int tid  = threadIdx.x;
  const int lane = tid & 63;
  const int wv   = tid >> 6;
  const int dsub = lane & 7;
  const int bl   = lane >> 3;
  const int icg  = blockIdx.x & 31;
  const int bg   = blockIdx.x >> 5;
  const int b    = bg * 8 + bl;
  const int i0   = (icg * 4 + wv) * 9;
  const int lb   = b * 16 + dsub * 2;

  __shared__ float red[4][8 * 168];   // cross-wave reduce, padded rows

  // V prologue: each lane squashes its own (b,o,d-pair) slice (R3-proven).
  float Vr[OO][2];
#pragma unroll
  for (int o = 0; o < OO; ++o) {
    const float2 a = *(const float2*)(r0 + ((size_t)b * OO + o) * DOUT + dsub * 2);
    float v0, v1;
    squash_pair(a.x, a.y, v0, v1);
    if (K == 2) {
      const float2 c = *(const float2*)(r1 + ((size_t)b * OO + o) * DOUT + dsub * 2);
      float u0, u1;
      squash_pair(c.x, c.y, u0, u1);
      v0 += u0; v1 += u1;              // b-linearity: t(V0+V1) = t(V0)+t(V1)
    }
    Vr[o][0] = v0; Vr[o][1] = v1;
  }

  float s[OO][2];
#pragma unroll
  for (int o = 0; o < OO; ++o) { s[o][0] = 0.f; s[o][1] = 0.f; }

#pragma unroll 1
  for (int ii = 0; ii < 9; ++ii) {
    const int i = i0 + ii;
    const __fp16* bp = xh16 + (size_t)i * (OO * 4096) + lb;

    h2 xv[OO];
#pragma unroll
    for (int o = 0; o < OO; ++o) xv[o] = *(const h2*)(bp + o * 4096);

    float xh[OO][2];
    float t[OO];
#pragma unroll
    for (int o = 0; o < OO; ++o) {
      xh[o][0] = (float)xv[o][0];
      xh[o][1] = (float)xv[o][1];
      t[o] = Vr[o][0] * xh[o][0] + Vr[o][1] * xh[o][1];
    }
#pragma unroll
    for (int o = 0; o < OO; ++o) {     // reduce over the 8 dsub lanes
      t[o] = dpp_add_xor1(t[o]);
      t[o] = dpp_add_xor2(t[o]);
      t[o] = swz_add_xor4(t[o]);
    }
    float sum = 0.f;
#pragma unroll
    for (int o = 0; o < OO; ++o) { t[o] = __expf(t[o]); sum += t[o]; }
    const float inv = __builtin_amdgcn_rcpf(sum);
#pragma unroll
    for (int o = 0; o < OO; ++o) {
      const float c = t[o] * inv;
      s[o][0] += c * xh[o][0];
      s[o][1] += c * xh[o][1];
    }
  }

  if (wv != 0) {
    float* rr = red[wv] + bl * 168;
#pragma unroll
    for (int o = 0; o < OO; ++o)
      *(float2*)&rr[o * 16 + dsub * 2] = make_float2(s[o][0], s[o][1]);
  }
  __syncthreads();
  if (wv == 0) {
    float* outp = plane + (size_t)b * (OO * DOUT);
#pragma unroll
    for (int o = 0; o < OO; ++o) {
      float a0 = s[o][0], a1 = s[o][1];
#pragma unroll
      for (int r = 1; r < 4; ++r) {
        const float2 v2 = *(const float2*)(red[r] + bl * 168 + o * 16 + dsub * 2);
        a0 += v2.x; a1 += v2.y;
      }
      unsafeAtomicAdd(&outp[o * 16 + dsub * 2],     a0);
      unsafeAtomicAdd(&outp[o * 16 + dsub * 2 + 1], a1);
    }
  }
}

// Final squash of plane2 -> out (proven).
__global__ __launch_bounds__(256) void final_kernel(
    const float* __restrict__ plane,   // [B*O*DOUT]
    float* __restrict__ out)           // fp32 [B*O*DOUT]
{
  const int idx = blockIdx.x * 256 + threadIdx.x;    // over B*O*DOUT = 40960
  const float s = plane[idx];

  float sq = s * s;
  sq += __shfl_xor(sq, 1);
  sq += __shfl_xor(sq, 2);
  sq += __shfl_xor(sq, 4);
  sq += __shfl_xor(sq, 8);
  const float mag = sqrtf(sq);
  out[idx] = sq / (1.f + sq) * (s / (mag + 1e-8f));
}

extern "C" void kernel_launch(void* const* d_in, const int* in_sizes, int n_in,
                              void* d_out, int out_size, void* d_ws, size_t ws_size,
                              hipStream_t stream) {
  const float* x = (const float*)d_in[0];   // fp32 [256,1152,8]
  const float* w = (const float*)d_in[1];   // fp32 [10,1152,16,8]
  float* outp = (float*)d_out;              // fp32 [256,10,16]

  const size_t P = (size_t)BB * OO * DOUT;  // 40960 floats per plane
  float* s0 = (float*)d_ws;                 // 3 accumulator planes
  float* s1 = s0 + P;
  float* s2 = s1 + P;
  __fp16* x16 = (__fp16*)(s2 + P);                 // 4.72 MB
  __fp16* w16 = x16 + (size_t)BB * II * 8;         // 3.54 MB (o-padded tiles)
  __fp16* xh16 = w16 + (size_t)II * 12 * 128;      // 94.4 MB [I][O][B][16]

  hipMemsetAsync(s0, 0, 3 * P * sizeof(float), stream);
  convert_kernel<<<5184, 256, 0, stream>>>(x, w, x16, w16);

  const int pg = 1024;                      // 32 icg (fast) x 32 bg
  const int fg = (int)(P / 256);            // 160 blocks

  einsum_kernel<<<pg, 256, 0, stream>>>(x16, w16, xh16, s0);
  route_kernel<1><<<pg, 256, 0, stream>>>(xh16, s0, nullptr, s1);
  route_kernel<2><<<pg, 256, 0, stream>>>(xh16, s0, s1, s2);
  final_kernel<<<fg, 256, 0, stream>>>(s2, outp);
}